// Round 23
// baseline (207.392 us; speedup 1.0000x reference)
//
#include <hip/hip_runtime.h>

#define K_CODES 1024
#define D_DIM   256
#define N_VEC   32768
#define BETA    0.25f
#define DECAY   0.99f
#define EPSV    1e-5f

// d_out layout (float32), offsets in elements
#define OFF_ZQ   0          // parks zf[n][d] (k_pt -> k_main/k_fix/k_dw2), overwritten by k_tail
#define OFF_IDX  8388608
#define OFF_LOSS 8421376
#define OFF_EMB  8421377
#define OFF_CS   8683521    // zeroed by k_main blk0; counts by k_merge/k_fix; new_cs by k_scan
#define OFF_EMAW 8684545    // B_swz fp16 (at +3 for 16B align) until k_merge zeroes; then dw -> new_ema_w

// ws layout (floats / ints), ~5.7 MB
#define WS_EMBT    0        // embT[d][j] fp32
#define WS_ENORM   262144   // 1024
#define WS_ELOMAX  263168
#define WS_EHIMAX  263169
#define WS_FIXCNT  263170
#define WS_S2      263172   // 32768 rows x 4 jq x float2 (u32 keys) = 262144 floats
#define WS_ZN2     1311748  // 32768
#define WS_ZLO2    1344516  // 32768
#define WS_FIXLIST 1377284  // 32768 ints; reused as BUCKET
#define WS_OFF     1410052
#define WS_POS     1411076
#define WS_CNT     1412100
#define WS_CHTAB   1413124  // 2048
#define WS_TC      1415172

#define CHUNK 32
#define DBIAS 512.0f        // per-row-constant shift making dist keys positive

typedef _Float16 f16;
typedef f16   f16x8 __attribute__((ext_vector_type(8)));
typedef float f32x4 __attribute__((ext_vector_type(4)));

// -------- fused: embT/enorm/B_swz (blocks 0..383) | zf transpose + norms (384..1407)
__global__ void k_pt(const float* __restrict__ z, const float* __restrict__ emb,
                     float* __restrict__ ws, float* __restrict__ out) {
    if (blockIdx.x == 0 && threadIdx.x == 0) *(int*)(ws + WS_FIXCNT) = 0;
    if (blockIdx.x < 256) {
        int j    = blockIdx.x * 4 + (threadIdx.x >> 6);
        int lane = threadIdx.x & 63;
        float4 v = reinterpret_cast<const float4*>(emb + j * D_DIM)[lane];
        ws[(lane * 4 + 0) * 1024 + j] = v.x;
        ws[(lane * 4 + 1) * 1024 + j] = v.y;
        ws[(lane * 4 + 2) * 1024 + j] = v.z;
        ws[(lane * 4 + 3) * 1024 + j] = v.w;
        float s = v.x * v.x + v.y * v.y + v.z * v.z + v.w * v.w;
        float hx = (float)(f16)v.x, hy = (float)(f16)v.y;
        float hz = (float)(f16)v.z, hw = (float)(f16)v.w;
        float lx = v.x - hx, ly = v.y - hy, lz = v.z - hz, lw = v.w - hw;
        float sl = lx * lx + ly * ly + lz * lz + lw * lw;
        float sh = hx * hx + hy * hy + hz * hz + hw * hw;
        #pragma unroll
        for (int o = 32; o > 0; o >>= 1) {
            s  += __shfl_xor(s,  o, 64);
            sl += __shfl_xor(sl, o, 64);
            sh += __shfl_xor(sh, o, 64);
        }
        if (lane == 0) {
            ws[WS_ENORM + j] = s;
            atomicMax((int*)(ws + WS_ELOMAX), __float_as_int(sqrtf(sl)));
            atomicMax((int*)(ws + WS_EHIMAX), __float_as_int(sqrtf(sh)));
        }
    } else if (blockIdx.x < 384) {
        int slot = (blockIdx.x - 256) * 256 + threadIdx.x;  // 32768 slots
        int lane = slot & 63;
        int kbjt = slot >> 6;
        int kb   = kbjt & 7;
        int jt   = kbjt >> 3;
        int j    = jt * 16 + (lane & 15);
        int d0   = kb * 32 + (lane >> 4) * 8;
        float4 e0 = *reinterpret_cast<const float4*>(emb + j * D_DIM + d0);
        float4 e1 = *reinterpret_cast<const float4*>(emb + j * D_DIM + d0 + 4);
        f16x8 w;
        w[0] = (f16)e0.x; w[1] = (f16)e0.y; w[2] = (f16)e0.z; w[3] = (f16)e0.w;
        w[4] = (f16)e1.x; w[5] = (f16)e1.y; w[6] = (f16)e1.z; w[7] = (f16)e1.w;
        f16* dst = (f16*)(out + OFF_EMAW + 3);   // +3 floats -> 16B aligned
        *reinterpret_cast<f16x8*>(dst + slot * 8) = w;
    } else {
        __shared__ float tile[32][257];          // 32.9 KB
        const int bid = blockIdx.x - 384;        // 1024 blocks x 32 rows
        const int n0  = bid * 32;
        const int b   = n0 >> 10;
        const int hw0 = n0 & 1023;
        const int tid = threadIdx.x;             // 256
        #pragma unroll 8
        for (int rep = 0; rep < 32; ++rep) {
            int elem = rep * 256 + tid;
            int d = elem >> 5, hwl = elem & 31;
            tile[hwl][d] = z[b * (D_DIM * 1024) + d * 1024 + hw0 + hwl];
        }
        __syncthreads();
        #pragma unroll 8
        for (int row = 0; row < 32; ++row)
            out[OFF_ZQ + (long)(n0 + row) * 256 + tid] = tile[row][tid];
        if (tid < 32) {
            float sn = 0.f, sl = 0.f;
            for (int d = 0; d < 256; ++d) {
                float v  = tile[tid][d];
                float lo = v - (float)(f16)v;
                sn += v * v; sl += lo * lo;
            }
            ws[WS_ZN2  + n0 + tid] = sn;
            ws[WS_ZLO2 + n0 + tid] = sl;
        }
    }
}

// ---------------------------------------------------------------- main (MFMA, 16 rows/wave,
//   grid 2048 = 512 rt x 4 jq, XCD-chunked mapping: all 4 jq of a rt share one XCD/L2)
__global__ __launch_bounds__(256, 2)
void k_main(float* __restrict__ out, float* __restrict__ ws) {
    __shared__ float els_s[256];

    const int tid  = threadIdx.x;     // 256 = 4 waves
    const int lane = tid & 63;
    const int w    = tid >> 6;        // 0..3
    const int orig = blockIdx.x;      // 2048
    const int xcd  = orig & 7;        // hw round-robin XCD assignment
    const int lid  = orig >> 3;       // 0..255 within this XCD's share
    const int rt   = xcd * 64 + (lid >> 2);   // 512 rowtiles, 64 per XCD
    const int jq   = lid & 3;                 // 4 j-quarters, same XCD per rt
    const int n0   = rt * 64;         // 64 rows per block
    const float* zf = out + OFF_ZQ;
    const f16* Bw = (const f16*)(out + OFF_EMAW + 3);

    if (orig == 0) {                  // zero CS + LOSS (consumed by k_merge and later)
        #pragma unroll
        for (int r = 0; r < 4; ++r) out[OFF_CS + r * 256 + tid] = 0.f;
        if (tid == 0) out[OFF_LOSS] = 0.f;
    }
    els_s[tid] = ws[WS_ENORM + jq * 256 + tid] + DBIAS;

    // ---- A fragments: named scalars (no array -> no scratch, rule #20)
    const int aoff = (lane >> 4) * 8;
    const int c    = lane & 15;
    const long arow = n0 + w * 16 + c;
    f16x8 a0, a1, a2, a3, a4, a5, a6, a7;
#define LOADA(KB, AV) { \
    float4 p0 = *reinterpret_cast<const float4*>(zf + arow * 256 + KB * 32 + aoff); \
    float4 p1 = *reinterpret_cast<const float4*>(zf + arow * 256 + KB * 32 + aoff + 4); \
    AV = (f16x8){(f16)p0.x, (f16)p0.y, (f16)p0.z, (f16)p0.w, \
                 (f16)p1.x, (f16)p1.y, (f16)p1.z, (f16)p1.w}; }
    LOADA(0, a0) LOADA(1, a1) LOADA(2, a2) LOADA(3, a3)
    LOADA(4, a4) LOADA(5, a5) LOADA(6, a6) LOADA(7, a7)
#undef LOADA
    __syncthreads();                  // els_s visible

    // top-2 state: 2 packed keys per acc row (8 u32 total)
    unsigned k1_0 = 0xFFFFFFFFu, k2_0 = 0xFFFFFFFFu;
    unsigned k1_1 = 0xFFFFFFFFu, k2_1 = 0xFFFFFFFFu;
    unsigned k1_2 = 0xFFFFFFFFu, k2_2 = 0xFFFFFFFFu;
    unsigned k1_3 = 0xFFFFFFFFu, k2_3 = 0xFFFFFFFFu;

    for (int pass = 0; pass < 8; ++pass) {       // 2 j-tiles (32 j) per pass; 8x32 = 256 j
        const int jt0 = jq * 16 + pass * 2;
        const f16* B0 = Bw + ((size_t)jt0 * 8 * 64 + lane) * 8;
        f32x4 acc0 = (f32x4){0.f, 0.f, 0.f, 0.f};
        f32x4 acc1 = (f32x4){0.f, 0.f, 0.f, 0.f};
#define KBSTEP(KB, AV) { \
        f16x8 b0 = *reinterpret_cast<const f16x8*>(B0 + (size_t)KB * 512); \
        f16x8 b1 = *reinterpret_cast<const f16x8*>(B0 + (size_t)(KB + 8) * 512); \
        acc0 = __builtin_amdgcn_mfma_f32_16x16x32_f16(AV, b0, acc0, 0, 0, 0); \
        acc1 = __builtin_amdgcn_mfma_f32_16x16x32_f16(AV, b1, acc1, 0, 0, 0); }
        KBSTEP(0, a0) KBSTEP(1, a1) KBSTEP(2, a2) KBSTEP(3, a3)
        KBSTEP(4, a4) KBSTEP(5, a5) KBSTEP(6, a6) KBSTEP(7, a7)
#undef KBSTEP
        const int jl0 = pass * 32 + c;
        const float en0 = els_s[jl0];            // biased: en + DBIAS > 0 always
        const float en1 = els_s[jl0 + 16];
        const unsigned jg0 = (unsigned)(jq * 256 + jl0);
        // key = (float bits of biased dist, low 10 bits cleared) | j
        // positive floats: uint order == float order; equal-quantized -> smaller j (np rule)
#define FOLD(EN, ACC, JJ, R) { \
        float _d = fmaf(-2.f, (ACC), (EN)); \
        unsigned _k = (__float_as_uint(_d) & 0xFFFFFC00u) | (JJ); \
        unsigned _mx = max(k1_##R, _k); \
        k1_##R = min(k1_##R, _k); \
        k2_##R = min(k2_##R, _mx); }
        FOLD(en0, acc0[0], jg0,       0) FOLD(en1, acc1[0], jg0 + 16u, 0)
        FOLD(en0, acc0[1], jg0,       1) FOLD(en1, acc1[1], jg0 + 16u, 1)
        FOLD(en0, acc0[2], jg0,       2) FOLD(en1, acc1[2], jg0 + 16u, 2)
        FOLD(en0, acc0[3], jg0,       3) FOLD(en1, acc1[3], jg0 + 16u, 3)
#undef FOLD
    }

    // ---- single cross-lane merge (within each 16-lane group) + S2 write (float2 of key bits)
#define MERGE(R, RIDX) { \
        unsigned K1 = k1_##R, K2 = k2_##R; \
        _Pragma("unroll") \
        for (int s = 1; s < 16; s <<= 1) { \
            unsigned o1 = (unsigned)__shfl_xor((int)K1, s, 64); \
            unsigned o2 = (unsigned)__shfl_xor((int)K2, s, 64); \
            unsigned mx = max(K1, o1); \
            K1 = min(K1, o1); \
            K2 = min(min(K2, o2), mx); \
        } \
        if (c == 0) { \
            int row = n0 + w * 16 + (lane >> 4) * 4 + RIDX; \
            *reinterpret_cast<float2*>(ws + WS_S2 + ((size_t)row * 4 + jq) * 2) = \
                (float2){__uint_as_float(K1), __uint_as_float(K2)}; } }
    MERGE(0, 0) MERGE(1, 1) MERGE(2, 2) MERGE(3, 3)
#undef MERGE
}

// ---- global top-2 merge + flag + counts + loss (unflagged) + zero EMAW
__global__ void k_merge(float* __restrict__ ws, float* __restrict__ out) {
    int n = blockIdx.x * 256 + threadIdx.x;      // 128 blocks -> 32768 threads
    const float2* S2 = reinterpret_cast<const float2*>(ws + WS_S2) + (size_t)n * 4;
    float2 ea = S2[0], eb = S2[1], ec = S2[2], ed = S2[3];
    unsigned k1 = __float_as_uint(ea.x), k2 = __float_as_uint(ea.y);
    unsigned o1, mx;
    o1 = __float_as_uint(eb.x); mx = max(k1, o1); k1 = min(k1, o1);
    k2 = min(min(k2, __float_as_uint(eb.y)), mx);
    o1 = __float_as_uint(ec.x); mx = max(k1, o1); k1 = min(k1, o1);
    k2 = min(min(k2, __float_as_uint(ec.y)), mx);
    o1 = __float_as_uint(ed.x); mx = max(k1, o1); k1 = min(k1, o1);
    k2 = min(min(k2, __float_as_uint(ed.y)), mx);
    int j1 = (int)(k1 & 0x3FFu);
    float d1 = __uint_as_float(k1 & 0xFFFFFC00u) - DBIAS;   // quantized en - 2 z.e
    float d2 = __uint_as_float(k2 & 0xFFFFFC00u) - DBIAS;
    out[OFF_IDX + n] = (float)j1;
    float zn2 = ws[WS_ZN2 + n];
    float margin = 4.f * (sqrtf(ws[WS_ZLO2 + n]) * ws[WS_EHIMAX] +
                          sqrtf(zn2) * ws[WS_ELOMAX]) + 0.05f
                 + 0.4f;                                     // key quantization slack
    if (d2 - d1 <= margin) {
        int p = atomicAdd((int*)(ws + WS_FIXCNT), 1);
        ((int*)(ws + WS_FIXLIST))[p] = n;        // k_fix counts + adds loss for these
    } else {
        atomicAdd(out + OFF_CS + j1, 1.0f);
        atomicAdd(out + OFF_LOSS, d1 + zn2);     // d_min = (||e||^2 - 2 z.e) + ||z||^2
    }
    // zero dw accumulator region: 262144 floats / 32768 threads = 2 float4 each
    #pragma unroll
    for (int r = 0; r < 2; ++r)
        *reinterpret_cast<float4*>(out + OFF_EMAW + ((size_t)n * 2 + r) * 4) =
            (float4){0.f, 0.f, 0.f, 0.f};
}

// ------------------------- exact recompute (8 rows/group, d-loop unrolled for ILP)
__global__ void k_fix(const float* __restrict__ ws_c, float* __restrict__ out) {
    __shared__ float zr[8][256];
    __shared__ float rd[8][4]; __shared__ int rj[8][4];
    const int tid = threadIdx.x;                 // 256
    const int cnt = *(const int*)(ws_c + WS_FIXCNT);
    const int* fixlist = (const int*)(ws_c + WS_FIXLIST);
    const int groups = (cnt + 7) >> 3;
    const float4 en = *reinterpret_cast<const float4*>(ws_c + WS_ENORM + tid * 4);

    for (int g = blockIdx.x; g < groups; g += gridDim.x) {
        int nrow[8];
        #pragma unroll
        for (int r = 0; r < 8; ++r) {
            int slot = g * 8 + r;
            nrow[r] = (slot < cnt) ? fixlist[slot] : -1;
        }
        #pragma unroll
        for (int r = 0; r < 8; ++r)
            zr[r][tid] = (nrow[r] >= 0) ? out[OFF_ZQ + (long)nrow[r] * 256 + tid] : 0.f;
        __syncthreads();

        float acc[8][4];
        #pragma unroll
        for (int r = 0; r < 8; ++r)
            #pragma unroll
            for (int q = 0; q < 4; ++q) acc[r][q] = 0.f;
        #pragma unroll 4
        for (int d = 0; d < 256; ++d) {          // unroll 4 -> 4 e-loads in flight
            float4 e = *reinterpret_cast<const float4*>(ws_c + WS_EMBT + d * 1024 + tid * 4);
            #pragma unroll
            for (int r = 0; r < 8; ++r) {
                float zd = zr[r][d];
                acc[r][0] += zd * e.x; acc[r][1] += zd * e.y;
                acc[r][2] += zd * e.z; acc[r][3] += zd * e.w;
            }
        }
        #pragma unroll
        for (int r = 0; r < 8; ++r) {
            float best = 3.4e38f; int bj = 0;
            #pragma unroll
            for (int q = 0; q < 4; ++q) {
                int j = tid * 4 + q;
                float v = ((const float*)&en)[q] - 2.f * acc[r][q];
                if (v < best || (v == best && j < bj)) { best = v; bj = j; }
            }
            #pragma unroll
            for (int o = 1; o < 64; o <<= 1) {
                float ov = __shfl_xor(best, o, 64);
                int   oj = __shfl_xor(bj, o, 64);
                if (ov < best || (ov == best && oj < bj)) { best = ov; bj = oj; }
            }
            if ((tid & 63) == 0) { rd[r][tid >> 6] = best; rj[r][tid >> 6] = bj; }
        }
        __syncthreads();
        if (tid < 8) {
            int r = tid;
            float v = rd[r][0]; int j = rj[r][0];
            #pragma unroll
            for (int ww = 1; ww < 4; ++ww)
                if (rd[r][ww] < v || (rd[r][ww] == v && rj[r][ww] < j)) { v = rd[r][ww]; j = rj[r][ww]; }
            int slot = g * 8 + r;
            if (slot < cnt) {
                int n = fixlist[slot];
                out[OFF_IDX + n] = (float)j;
                atomicAdd(out + OFF_CS + j, 1.0f);
                atomicAdd(out + OFF_LOSS, v + ws_c[WS_ZN2 + n]);   // exact d_min
            }
        }
        __syncthreads();
    }
}

// ------------------- scan: offsets + chunk table + new_cs + finalize loss
__global__ void k_scan(const float* __restrict__ ema_cs, float* __restrict__ ws,
                       float* __restrict__ out) {
    __shared__ float s[K_CODES];
    int tid = threadIdx.x;                       // 1024
    float cntf = out[OFF_CS + tid];
    int   cnt  = (int)cntf;
    float raw  = ema_cs[tid] * DECAY + 0.01f * cntf;

    s[tid] = cntf;
    __syncthreads();
    for (int off = 1; off < 1024; off <<= 1) {
        float v = (tid >= off) ? s[tid - off] : 0.f;
        __syncthreads();
        s[tid] += v;
        __syncthreads();
    }
    int excl = (int)(s[tid] - cntf);
    ((int*)(ws + WS_OFF))[tid] = excl;
    ((int*)(ws + WS_POS))[tid] = excl;
    ((int*)(ws + WS_CNT))[tid] = cnt;
    __syncthreads();

    int nch = (cnt + CHUNK - 1) / CHUNK;
    s[tid] = (float)nch;
    __syncthreads();
    for (int off = 1; off < 1024; off <<= 1) {
        float v = (tid >= off) ? s[tid - off] : 0.f;
        __syncthreads();
        s[tid] += v;
        __syncthreads();
    }
    int chexcl = (int)s[tid] - nch;
    int* chtab = (int*)(ws + WS_CHTAB);
    for (int k = 0; k < nch; ++k)
        chtab[chexcl + k] = (tid << 16) | k;
    if (tid == 1023) *(int*)(ws + WS_TC) = chexcl + nch;
    __syncthreads();

    s[tid] = raw;
    __syncthreads();
    for (int st = 512; st > 0; st >>= 1) {
        if (tid < st) s[tid] += s[tid + st];
        __syncthreads();
    }
    float ntot = s[0];
    out[OFF_CS + tid] = (raw + EPSV) / (ntot + K_CODES * EPSV) * ntot;
    if (tid == 0)
        out[OFF_LOSS] = out[OFF_LOSS] * (BETA / (float)(N_VEC * D_DIM));
}

// ---------------------------------------------------------------- scatter into buckets
__global__ void k_scatter(const float* __restrict__ out_c, float* __restrict__ ws) {
    int n = blockIdx.x * 256 + threadIdx.x;      // 128 blocks
    int j = (int)out_c[OFF_IDX + n];
    int p = atomicAdd((int*)(ws + WS_POS) + j, 1);
    ((int*)(ws + WS_FIXLIST))[p] = n;
}

// ---------------------------------------------------------------- dw partial sums (chunked)
__global__ void k_dw2(const float* __restrict__ ws, float* __restrict__ out) {
    __shared__ int midx[CHUNK];
    const int b = blockIdx.x;                    // 2048 blocks
    if (b >= *(const int*)(ws + WS_TC)) return;
    const int tab = ((const int*)(ws + WS_CHTAB))[b];
    const int j   = tab >> 16;
    const int lc  = tab & 0xffff;
    const int off = ((const int*)(ws + WS_OFF))[j];
    const int cnt = ((const int*)(ws + WS_CNT))[j];
    const int base = lc * CHUNK;
    const int m    = min(CHUNK, cnt - base);
    const int tid  = threadIdx.x;                // 256: d = tid
    if (tid < CHUNK)
        midx[tid] = (tid < m) ? ((const int*)(ws + WS_FIXLIST))[off + base + tid] : 0;
    __syncthreads();
    float acc = 0.f;
    for (int i = 0; i < m; ++i)
        acc += out[OFF_ZQ + (long)midx[i] * 256 + tid];
    atomicAdd(out + OFF_EMAW + j * 256 + tid, acc);
}

// -------------------- fused tail: new_ema_w/new_embedding (blk<256) | z_q gather
__global__ void k_tail(const float* __restrict__ emb, const float* __restrict__ ema_w,
                       float* __restrict__ out) {
    const int tid = threadIdx.x;                 // 256
    if (blockIdx.x < 256) {
        int i4 = blockIdx.x * 256 + tid;         // 65536 float4
        int j  = i4 >> 6;
        float4 dw = *reinterpret_cast<float4*>(out + OFF_EMAW + i4 * 4);
        float4 ew = *reinterpret_cast<const float4*>(ema_w + i4 * 4);
        float inv = 1.f / out[OFF_CS + j];
        float4 nw = {ew.x * DECAY + 0.01f * dw.x, ew.y * DECAY + 0.01f * dw.y,
                     ew.z * DECAY + 0.01f * dw.z, ew.w * DECAY + 0.01f * dw.w};
        *reinterpret_cast<float4*>(out + OFF_EMAW + i4 * 4) = nw;
        float4 nb = {nw.x * inv, nw.y * inv, nw.z * inv, nw.w * inv};
        *reinterpret_cast<float4*>(out + OFF_EMB + i4 * 4) = nb;
    } else {
        __shared__ float erows[32][257];
        __shared__ int js[32];
        const int n0  = (blockIdx.x - 256) * 32; // 1024 blocks
        const int b   = n0 >> 10;
        const int hw0 = n0 & 1023;
        if (tid < 32) js[tid] = (int)out[OFF_IDX + n0 + tid];
        __syncthreads();
        #pragma unroll 4
        for (int r = 0; r < 32; ++r)
            erows[r][tid] = emb[js[r] * D_DIM + tid];
        __syncthreads();
        const long zqb = (long)b * (D_DIM * 1024) + hw0;
        #pragma unroll 4
        for (int rep = 0; rep < 32; ++rep) {
            int elem = rep * 256 + tid;
            int d    = elem >> 5;
            int nl   = elem & 31;
            out[OFF_ZQ + zqb + d * 1024 + nl] = erows[nl][d];
        }
    }
}

// ---------------------------------------------------------------- launch
extern "C" void kernel_launch(void* const* d_in, const int* in_sizes, int n_in,
                              void* d_out, int out_size, void* d_ws, size_t ws_size,
                              hipStream_t stream) {
    const float* z      = (const float*)d_in[0];
    const float* emb    = (const float*)d_in[1];
    const float* ema_cs = (const float*)d_in[2];
    const float* ema_w  = (const float*)d_in[3];
    float* out = (float*)d_out;
    float* ws  = (float*)d_ws;                   // ~5.7 MB used

    hipLaunchKernelGGL(k_pt,      dim3(1408), dim3(256),  0, stream, z, emb, ws, out);
    hipLaunchKernelGGL(k_main,    dim3(2048), dim3(256),  0, stream, out, ws);
    hipLaunchKernelGGL(k_merge,   dim3(128),  dim3(256),  0, stream, ws, out);
    hipLaunchKernelGGL(k_fix,     dim3(512),  dim3(256),  0, stream, ws, out);
    hipLaunchKernelGGL(k_scan,    dim3(1),    dim3(1024), 0, stream, ema_cs, ws, out);
    hipLaunchKernelGGL(k_scatter, dim3(128),  dim3(256),  0, stream, out, ws);
    hipLaunchKernelGGL(k_dw2,     dim3(2048), dim3(256),  0, stream, ws, out);
    hipLaunchKernelGGL(k_tail,    dim3(1280), dim3(256),  0, stream, emb, ema_w, out);
}

// Round 24
// 188.702 us; speedup vs baseline: 1.0990x; 1.0990x over previous
//
#include <hip/hip_runtime.h>

#define K_CODES 1024
#define D_DIM   256
#define N_VEC   32768
#define BETA    0.25f
#define DECAY   0.99f
#define EPSV    1e-5f

// d_out layout (float32), offsets in elements
#define OFF_ZQ   0          // parks zf[n][d] (k_pt -> k_main/k_fix/k_dw2), overwritten by k_tail
#define OFF_IDX  8388608
#define OFF_LOSS 8421376
#define OFF_EMB  8421377
#define OFF_CS   8683521    // zeroed by k_main blk0; counts by k_merge/k_fix; new_cs by k_scan
#define OFF_EMAW 8684545    // B_swz fp16 (at +3 for 16B align) until k_merge zeroes; then dw -> new_ema_w

// ws layout (floats / ints), ~5.7 MB
#define WS_EMBT    0        // embT[d][j] fp32
#define WS_ENORM   262144   // 1024
#define WS_ELOMAX  263168
#define WS_EHIMAX  263169
#define WS_FIXCNT  263170
#define WS_S2      263172   // 32768 rows x 2 jh x float2 (u32 keys)
#define WS_ZN2     1311748  // 32768
#define WS_ZLO2    1344516  // 32768
#define WS_FIXLIST 1377284  // 32768 ints; reused as BUCKET
#define WS_OFF     1410052
#define WS_POS     1411076
#define WS_CNT     1412100
#define WS_CHTAB   1413124  // 2048
#define WS_TC      1415172

#define CHUNK 32
#define DBIAS 512.0f        // per-row-constant shift making dist keys positive

typedef _Float16 f16;
typedef f16   f16x8 __attribute__((ext_vector_type(8)));
typedef float f32x4 __attribute__((ext_vector_type(4)));

// -------- fused: embT/enorm/B_swz (blocks 0..383) | zf transpose + norms (384..1407)
__global__ void k_pt(const float* __restrict__ z, const float* __restrict__ emb,
                     float* __restrict__ ws, float* __restrict__ out) {
    if (blockIdx.x == 0 && threadIdx.x == 0) *(int*)(ws + WS_FIXCNT) = 0;
    if (blockIdx.x < 256) {
        int j    = blockIdx.x * 4 + (threadIdx.x >> 6);
        int lane = threadIdx.x & 63;
        float4 v = reinterpret_cast<const float4*>(emb + j * D_DIM)[lane];
        ws[(lane * 4 + 0) * 1024 + j] = v.x;
        ws[(lane * 4 + 1) * 1024 + j] = v.y;
        ws[(lane * 4 + 2) * 1024 + j] = v.z;
        ws[(lane * 4 + 3) * 1024 + j] = v.w;
        float s = v.x * v.x + v.y * v.y + v.z * v.z + v.w * v.w;
        float hx = (float)(f16)v.x, hy = (float)(f16)v.y;
        float hz = (float)(f16)v.z, hw = (float)(f16)v.w;
        float lx = v.x - hx, ly = v.y - hy, lz = v.z - hz, lw = v.w - hw;
        float sl = lx * lx + ly * ly + lz * lz + lw * lw;
        float sh = hx * hx + hy * hy + hz * hz + hw * hw;
        #pragma unroll
        for (int o = 32; o > 0; o >>= 1) {
            s  += __shfl_xor(s,  o, 64);
            sl += __shfl_xor(sl, o, 64);
            sh += __shfl_xor(sh, o, 64);
        }
        if (lane == 0) {
            ws[WS_ENORM + j] = s;
            atomicMax((int*)(ws + WS_ELOMAX), __float_as_int(sqrtf(sl)));
            atomicMax((int*)(ws + WS_EHIMAX), __float_as_int(sqrtf(sh)));
        }
    } else if (blockIdx.x < 384) {
        int slot = (blockIdx.x - 256) * 256 + threadIdx.x;  // 32768 slots
        int lane = slot & 63;
        int kbjt = slot >> 6;
        int kb   = kbjt & 7;
        int jt   = kbjt >> 3;
        int j    = jt * 16 + (lane & 15);
        int d0   = kb * 32 + (lane >> 4) * 8;
        float4 e0 = *reinterpret_cast<const float4*>(emb + j * D_DIM + d0);
        float4 e1 = *reinterpret_cast<const float4*>(emb + j * D_DIM + d0 + 4);
        f16x8 w;
        w[0] = (f16)e0.x; w[1] = (f16)e0.y; w[2] = (f16)e0.z; w[3] = (f16)e0.w;
        w[4] = (f16)e1.x; w[5] = (f16)e1.y; w[6] = (f16)e1.z; w[7] = (f16)e1.w;
        f16* dst = (f16*)(out + OFF_EMAW + 3);   // +3 floats -> 16B aligned
        *reinterpret_cast<f16x8*>(dst + slot * 8) = w;
    } else {
        __shared__ float tile[32][257];          // 32.9 KB
        const int bid = blockIdx.x - 384;        // 1024 blocks x 32 rows
        const int n0  = bid * 32;
        const int b   = n0 >> 10;
        const int hw0 = n0 & 1023;
        const int tid = threadIdx.x;             // 256
        #pragma unroll 8
        for (int rep = 0; rep < 32; ++rep) {
            int elem = rep * 256 + tid;
            int d = elem >> 5, hwl = elem & 31;
            tile[hwl][d] = z[b * (D_DIM * 1024) + d * 1024 + hw0 + hwl];
        }
        __syncthreads();
        #pragma unroll 8
        for (int row = 0; row < 32; ++row)
            out[OFF_ZQ + (long)(n0 + row) * 256 + tid] = tile[row][tid];
        if (tid < 32) {
            float sn = 0.f, sl = 0.f;
            for (int d = 0; d < 256; ++d) {
                float v  = tile[tid][d];
                float lo = v - (float)(f16)v;
                sn += v * v; sl += lo * lo;
            }
            ws[WS_ZN2  + n0 + tid] = sn;
            ws[WS_ZLO2 + n0 + tid] = sl;
        }
    }
}

// ---------------------------------------------------------------- main (MFMA, 16 rows/wave,
//   16 passes x 2 j-tiles; top-2 as packed u32 keys: (dist bits & ~0x3FF) | j)
__global__ __launch_bounds__(256, 2)
void k_main(float* __restrict__ out, float* __restrict__ ws) {
    __shared__ float els_s[512];

    const int tid  = threadIdx.x;     // 256 = 4 waves
    const int lane = tid & 63;
    const int w    = tid >> 6;        // 0..3
    const int bid  = blockIdx.x;      // 1024 = 512 rowtiles x 2 j-halves
    const int rt   = bid >> 1;
    const int jh   = bid & 1;
    const int n0   = rt * 64;         // 64 rows per block
    const float* zf = out + OFF_ZQ;
    const f16* Bw = (const f16*)(out + OFF_EMAW + 3);

    if (bid == 0) {                   // zero CS + LOSS (consumed by k_merge and later)
        #pragma unroll
        for (int r = 0; r < 4; ++r) out[OFF_CS + r * 256 + tid] = 0.f;
        if (tid == 0) out[OFF_LOSS] = 0.f;
    }
    els_s[tid]       = ws[WS_ENORM + jh * 512 + tid] + DBIAS;
    els_s[tid + 256] = ws[WS_ENORM + jh * 512 + tid + 256] + DBIAS;

    // ---- A fragments: named scalars (no array -> no scratch, rule #20)
    const int aoff = (lane >> 4) * 8;
    const int c    = lane & 15;
    const long arow = n0 + w * 16 + c;
    f16x8 a0, a1, a2, a3, a4, a5, a6, a7;
#define LOADA(KB, AV) { \
    float4 p0 = *reinterpret_cast<const float4*>(zf + arow * 256 + KB * 32 + aoff); \
    float4 p1 = *reinterpret_cast<const float4*>(zf + arow * 256 + KB * 32 + aoff + 4); \
    AV = (f16x8){(f16)p0.x, (f16)p0.y, (f16)p0.z, (f16)p0.w, \
                 (f16)p1.x, (f16)p1.y, (f16)p1.z, (f16)p1.w}; }
    LOADA(0, a0) LOADA(1, a1) LOADA(2, a2) LOADA(3, a3)
    LOADA(4, a4) LOADA(5, a5) LOADA(6, a6) LOADA(7, a7)
#undef LOADA
    __syncthreads();                  // els_s visible

    // top-2 state: 2 packed keys per acc row (8 u32 total)
    unsigned k1_0 = 0xFFFFFFFFu, k2_0 = 0xFFFFFFFFu;
    unsigned k1_1 = 0xFFFFFFFFu, k2_1 = 0xFFFFFFFFu;
    unsigned k1_2 = 0xFFFFFFFFu, k2_2 = 0xFFFFFFFFu;
    unsigned k1_3 = 0xFFFFFFFFu, k2_3 = 0xFFFFFFFFu;

    for (int pass = 0; pass < 16; ++pass) {      // 2 j-tiles (32 j) per pass; 16x32 = 512 j
        const int jt0 = jh * 32 + pass * 2;
        const f16* B0 = Bw + ((size_t)jt0 * 8 * 64 + lane) * 8;
        f32x4 acc0 = (f32x4){0.f, 0.f, 0.f, 0.f};
        f32x4 acc1 = (f32x4){0.f, 0.f, 0.f, 0.f};
#define KBSTEP(KB, AV) { \
        f16x8 b0 = *reinterpret_cast<const f16x8*>(B0 + (size_t)KB * 512); \
        f16x8 b1 = *reinterpret_cast<const f16x8*>(B0 + (size_t)(KB + 8) * 512); \
        acc0 = __builtin_amdgcn_mfma_f32_16x16x32_f16(AV, b0, acc0, 0, 0, 0); \
        acc1 = __builtin_amdgcn_mfma_f32_16x16x32_f16(AV, b1, acc1, 0, 0, 0); }
        KBSTEP(0, a0) KBSTEP(1, a1) KBSTEP(2, a2) KBSTEP(3, a3)
        KBSTEP(4, a4) KBSTEP(5, a5) KBSTEP(6, a6) KBSTEP(7, a7)
#undef KBSTEP
        const int jl0 = pass * 32 + c;
        const float en0 = els_s[jl0];            // biased: en + DBIAS > 0 always
        const float en1 = els_s[jl0 + 16];
        const unsigned jg0 = (unsigned)(jh * 512 + jl0);
        // key = (float bits of biased dist, low 10 bits cleared) | j
        // positive floats: uint order == float order; equal-quantized -> smaller j (np rule)
#define FOLD(EN, ACC, JJ, R) { \
        float _d = fmaf(-2.f, (ACC), (EN)); \
        unsigned _k = (__float_as_uint(_d) & 0xFFFFFC00u) | (JJ); \
        unsigned _mx = max(k1_##R, _k); \
        k1_##R = min(k1_##R, _k); \
        k2_##R = min(k2_##R, _mx); }
        FOLD(en0, acc0[0], jg0,       0) FOLD(en1, acc1[0], jg0 + 16u, 0)
        FOLD(en0, acc0[1], jg0,       1) FOLD(en1, acc1[1], jg0 + 16u, 1)
        FOLD(en0, acc0[2], jg0,       2) FOLD(en1, acc1[2], jg0 + 16u, 2)
        FOLD(en0, acc0[3], jg0,       3) FOLD(en1, acc1[3], jg0 + 16u, 3)
#undef FOLD
    }

    // ---- single cross-lane merge (within each 16-lane group) + S2 write (float2 of key bits)
#define MERGE(R, RIDX) { \
        unsigned K1 = k1_##R, K2 = k2_##R; \
        _Pragma("unroll") \
        for (int s = 1; s < 16; s <<= 1) { \
            unsigned o1 = (unsigned)__shfl_xor((int)K1, s, 64); \
            unsigned o2 = (unsigned)__shfl_xor((int)K2, s, 64); \
            unsigned mx = max(K1, o1); \
            K1 = min(K1, o1); \
            K2 = min(min(K2, o2), mx); \
        } \
        if (c == 0) { \
            int row = n0 + w * 16 + (lane >> 4) * 4 + RIDX; \
            *reinterpret_cast<float2*>(ws + WS_S2 + ((size_t)row * 2 + jh) * 2) = \
                (float2){__uint_as_float(K1), __uint_as_float(K2)}; } }
    MERGE(0, 0) MERGE(1, 1) MERGE(2, 2) MERGE(3, 3)
#undef MERGE
}

// ---- global top-2 merge + flag + counts + loss (unflagged) + zero EMAW
__global__ void k_merge(float* __restrict__ ws, float* __restrict__ out) {
    int n = blockIdx.x * 256 + threadIdx.x;      // 128 blocks -> 32768 threads
    const float2* S2 = reinterpret_cast<const float2*>(ws + WS_S2) + (size_t)n * 2;
    float2 ea = S2[0], eb = S2[1];
    unsigned k1a = __float_as_uint(ea.x), k2a = __float_as_uint(ea.y);
    unsigned k1b = __float_as_uint(eb.x), k2b = __float_as_uint(eb.y);
    unsigned mx = max(k1a, k1b);
    unsigned k1 = min(k1a, k1b);
    unsigned k2 = min(min(k2a, k2b), mx);
    int j1 = (int)(k1 & 0x3FFu);
    float d1 = __uint_as_float(k1 & 0xFFFFFC00u) - DBIAS;   // quantized en - 2 z.e
    float d2 = __uint_as_float(k2 & 0xFFFFFC00u) - DBIAS;
    out[OFF_IDX + n] = (float)j1;
    float zn2 = ws[WS_ZN2 + n];
    float margin = 4.f * (sqrtf(ws[WS_ZLO2 + n]) * ws[WS_EHIMAX] +
                          sqrtf(zn2) * ws[WS_ELOMAX]) + 0.05f
                 + 0.4f;                                     // key quantization slack
    if (d2 - d1 <= margin) {
        int p = atomicAdd((int*)(ws + WS_FIXCNT), 1);
        ((int*)(ws + WS_FIXLIST))[p] = n;        // k_fix counts + adds loss for these
    } else {
        atomicAdd(out + OFF_CS + j1, 1.0f);
        atomicAdd(out + OFF_LOSS, d1 + zn2);     // d_min = (||e||^2 - 2 z.e) + ||z||^2
    }
    // zero dw accumulator region: 262144 floats / 32768 threads = 2 float4 each
    #pragma unroll
    for (int r = 0; r < 2; ++r)
        *reinterpret_cast<float4*>(out + OFF_EMAW + ((size_t)n * 2 + r) * 4) =
            (float4){0.f, 0.f, 0.f, 0.f};
}

// ------------------------- exact recompute (8 rows/group, d-loop unrolled for ILP)
__global__ void k_fix(const float* __restrict__ ws_c, float* __restrict__ out) {
    __shared__ float zr[8][256];
    __shared__ float rd[8][4]; __shared__ int rj[8][4];
    const int tid = threadIdx.x;                 // 256
    const int cnt = *(const int*)(ws_c + WS_FIXCNT);
    const int* fixlist = (const int*)(ws_c + WS_FIXLIST);
    const int groups = (cnt + 7) >> 3;
    const float4 en = *reinterpret_cast<const float4*>(ws_c + WS_ENORM + tid * 4);

    for (int g = blockIdx.x; g < groups; g += gridDim.x) {
        int nrow[8];
        #pragma unroll
        for (int r = 0; r < 8; ++r) {
            int slot = g * 8 + r;
            nrow[r] = (slot < cnt) ? fixlist[slot] : -1;
        }
        #pragma unroll
        for (int r = 0; r < 8; ++r)
            zr[r][tid] = (nrow[r] >= 0) ? out[OFF_ZQ + (long)nrow[r] * 256 + tid] : 0.f;
        __syncthreads();

        float acc[8][4];
        #pragma unroll
        for (int r = 0; r < 8; ++r)
            #pragma unroll
            for (int q = 0; q < 4; ++q) acc[r][q] = 0.f;
        #pragma unroll 4
        for (int d = 0; d < 256; ++d) {          // unroll 4 -> 4 e-loads in flight
            float4 e = *reinterpret_cast<const float4*>(ws_c + WS_EMBT + d * 1024 + tid * 4);
            #pragma unroll
            for (int r = 0; r < 8; ++r) {
                float zd = zr[r][d];
                acc[r][0] += zd * e.x; acc[r][1] += zd * e.y;
                acc[r][2] += zd * e.z; acc[r][3] += zd * e.w;
            }
        }
        #pragma unroll
        for (int r = 0; r < 8; ++r) {
            float best = 3.4e38f; int bj = 0;
            #pragma unroll
            for (int q = 0; q < 4; ++q) {
                int j = tid * 4 + q;
                float v = ((const float*)&en)[q] - 2.f * acc[r][q];
                if (v < best || (v == best && j < bj)) { best = v; bj = j; }
            }
            #pragma unroll
            for (int o = 1; o < 64; o <<= 1) {
                float ov = __shfl_xor(best, o, 64);
                int   oj = __shfl_xor(bj, o, 64);
                if (ov < best || (ov == best && oj < bj)) { best = ov; bj = oj; }
            }
            if ((tid & 63) == 0) { rd[r][tid >> 6] = best; rj[r][tid >> 6] = bj; }
        }
        __syncthreads();
        if (tid < 8) {
            int r = tid;
            float v = rd[r][0]; int j = rj[r][0];
            #pragma unroll
            for (int ww = 1; ww < 4; ++ww)
                if (rd[r][ww] < v || (rd[r][ww] == v && rj[r][ww] < j)) { v = rd[r][ww]; j = rj[r][ww]; }
            int slot = g * 8 + r;
            if (slot < cnt) {
                int n = fixlist[slot];
                out[OFF_IDX + n] = (float)j;
                atomicAdd(out + OFF_CS + j, 1.0f);
                atomicAdd(out + OFF_LOSS, v + ws_c[WS_ZN2 + n]);   // exact d_min
            }
        }
        __syncthreads();
    }
}

// ------------------- scan: offsets + chunk table + new_cs + finalize loss
__global__ void k_scan(const float* __restrict__ ema_cs, float* __restrict__ ws,
                       float* __restrict__ out) {
    __shared__ float s[K_CODES];
    int tid = threadIdx.x;                       // 1024
    float cntf = out[OFF_CS + tid];
    int   cnt  = (int)cntf;
    float raw  = ema_cs[tid] * DECAY + 0.01f * cntf;

    s[tid] = cntf;
    __syncthreads();
    for (int off = 1; off < 1024; off <<= 1) {
        float v = (tid >= off) ? s[tid - off] : 0.f;
        __syncthreads();
        s[tid] += v;
        __syncthreads();
    }
    int excl = (int)(s[tid] - cntf);
    ((int*)(ws + WS_OFF))[tid] = excl;
    ((int*)(ws + WS_POS))[tid] = excl;
    ((int*)(ws + WS_CNT))[tid] = cnt;
    __syncthreads();

    int nch = (cnt + CHUNK - 1) / CHUNK;
    s[tid] = (float)nch;
    __syncthreads();
    for (int off = 1; off < 1024; off <<= 1) {
        float v = (tid >= off) ? s[tid - off] : 0.f;
        __syncthreads();
        s[tid] += v;
        __syncthreads();
    }
    int chexcl = (int)s[tid] - nch;
    int* chtab = (int*)(ws + WS_CHTAB);
    for (int k = 0; k < nch; ++k)
        chtab[chexcl + k] = (tid << 16) | k;
    if (tid == 1023) *(int*)(ws + WS_TC) = chexcl + nch;
    __syncthreads();

    s[tid] = raw;
    __syncthreads();
    for (int st = 512; st > 0; st >>= 1) {
        if (tid < st) s[tid] += s[tid + st];
        __syncthreads();
    }
    float ntot = s[0];
    out[OFF_CS + tid] = (raw + EPSV) / (ntot + K_CODES * EPSV) * ntot;
    if (tid == 0)
        out[OFF_LOSS] = out[OFF_LOSS] * (BETA / (float)(N_VEC * D_DIM));
}

// ---------------------------------------------------------------- scatter into buckets
__global__ void k_scatter(const float* __restrict__ out_c, float* __restrict__ ws) {
    int n = blockIdx.x * 256 + threadIdx.x;      // 128 blocks
    int j = (int)out_c[OFF_IDX + n];
    int p = atomicAdd((int*)(ws + WS_POS) + j, 1);
    ((int*)(ws + WS_FIXLIST))[p] = n;
}

// ---------------------------------------------------------------- dw partial sums (chunked)
__global__ void k_dw2(const float* __restrict__ ws, float* __restrict__ out) {
    __shared__ int midx[CHUNK];
    const int b = blockIdx.x;                    // 2048 blocks
    if (b >= *(const int*)(ws + WS_TC)) return;
    const int tab = ((const int*)(ws + WS_CHTAB))[b];
    const int j   = tab >> 16;
    const int lc  = tab & 0xffff;
    const int off = ((const int*)(ws + WS_OFF))[j];
    const int cnt = ((const int*)(ws + WS_CNT))[j];
    const int base = lc * CHUNK;
    const int m    = min(CHUNK, cnt - base);
    const int tid  = threadIdx.x;                // 256: d = tid
    if (tid < CHUNK)
        midx[tid] = (tid < m) ? ((const int*)(ws + WS_FIXLIST))[off + base + tid] : 0;
    __syncthreads();
    float acc = 0.f;
    for (int i = 0; i < m; ++i)
        acc += out[OFF_ZQ + (long)midx[i] * 256 + tid];
    atomicAdd(out + OFF_EMAW + j * 256 + tid, acc);
}

// -------------------- fused tail: new_ema_w/new_embedding (blk<256) | z_q gather
__global__ void k_tail(const float* __restrict__ emb, const float* __restrict__ ema_w,
                       float* __restrict__ out) {
    const int tid = threadIdx.x;                 // 256
    if (blockIdx.x < 256) {
        int i4 = blockIdx.x * 256 + tid;         // 65536 float4
        int j  = i4 >> 6;
        float4 dw = *reinterpret_cast<float4*>(out + OFF_EMAW + i4 * 4);
        float4 ew = *reinterpret_cast<const float4*>(ema_w + i4 * 4);
        float inv = 1.f / out[OFF_CS + j];
        float4 nw = {ew.x * DECAY + 0.01f * dw.x, ew.y * DECAY + 0.01f * dw.y,
                     ew.z * DECAY + 0.01f * dw.z, ew.w * DECAY + 0.01f * dw.w};
        *reinterpret_cast<float4*>(out + OFF_EMAW + i4 * 4) = nw;
        float4 nb = {nw.x * inv, nw.y * inv, nw.z * inv, nw.w * inv};
        *reinterpret_cast<float4*>(out + OFF_EMB + i4 * 4) = nb;
    } else {
        __shared__ float erows[32][257];
        __shared__ int js[32];
        const int n0  = (blockIdx.x - 256) * 32; // 1024 blocks
        const int b   = n0 >> 10;
        const int hw0 = n0 & 1023;
        if (tid < 32) js[tid] = (int)out[OFF_IDX + n0 + tid];
        __syncthreads();
        #pragma unroll 4
        for (int r = 0; r < 32; ++r)
            erows[r][tid] = emb[js[r] * D_DIM + tid];
        __syncthreads();
        const long zqb = (long)b * (D_DIM * 1024) + hw0;
        #pragma unroll 4
        for (int rep = 0; rep < 32; ++rep) {
            int elem = rep * 256 + tid;
            int d    = elem >> 5;
            int nl   = elem & 31;
            out[OFF_ZQ + zqb + d * 1024 + nl] = erows[nl][d];
        }
    }
}

// ---------------------------------------------------------------- launch
extern "C" void kernel_launch(void* const* d_in, const int* in_sizes, int n_in,
                              void* d_out, int out_size, void* d_ws, size_t ws_size,
                              hipStream_t stream) {
    const float* z      = (const float*)d_in[0];
    const float* emb    = (const float*)d_in[1];
    const float* ema_cs = (const float*)d_in[2];
    const float* ema_w  = (const float*)d_in[3];
    float* out = (float*)d_out;
    float* ws  = (float*)d_ws;                   // ~5.7 MB used

    hipLaunchKernelGGL(k_pt,      dim3(1408), dim3(256),  0, stream, z, emb, ws, out);
    hipLaunchKernelGGL(k_main,    dim3(1024), dim3(256),  0, stream, out, ws);
    hipLaunchKernelGGL(k_merge,   dim3(128),  dim3(256),  0, stream, ws, out);
    hipLaunchKernelGGL(k_fix,     dim3(512),  dim3(256),  0, stream, ws, out);
    hipLaunchKernelGGL(k_scan,    dim3(1),    dim3(1024), 0, stream, ema_cs, ws, out);
    hipLaunchKernelGGL(k_scatter, dim3(128),  dim3(256),  0, stream, out, ws);
    hipLaunchKernelGGL(k_dw2,     dim3(2048), dim3(256),  0, stream, ws, out);
    hipLaunchKernelGGL(k_tail,    dim3(1280), dim3(256),  0, stream, emb, ema_w, out);
}